// Round 1
// baseline (152453.113 us; speedup 1.0000x reference)
//
#include <hip/hip_runtime.h>
#include <math.h>

#define L_SEQ 8192
#define I_DIM 256
#define H_DIM 2048
#define NWG0  64
#define NWG1  128
#define NWG   (NWG0 + NWG1)
#define TPB   512
#define NSTEP (L_SEQ + 1)   // skewed 2-layer pipeline: 8193 compute steps

// ws layout (bytes): [0] runctr | [256..1024) slots | [1024) h0[2][2048] | [+16K) h1[2][2048]

__device__ __forceinline__ void grid_barrier(unsigned* slots, int wg, int tid, unsigned value) {
  __syncthreads();  // all this WG's stores drained to L2 (vmcnt0 before s_barrier)
  if (tid == 0)
    __hip_atomic_store(&slots[wg], value, __ATOMIC_RELEASE, __HIP_MEMORY_SCOPE_AGENT);
  if (tid < NWG) {
    // monotone-in-run values; (int)(slot - value) >= 0 tolerates run-ahead writers.
    while ((int)(__hip_atomic_load(&slots[tid], __ATOMIC_RELAXED, __HIP_MEMORY_SCOPE_AGENT) - value) < 0)
      __builtin_amdgcn_s_sleep(1);
  }
  __syncthreads();
  __builtin_amdgcn_fence(__ATOMIC_ACQUIRE, "agent");  // invalidate stale L1/L2 before reading remote h
}

__global__ __launch_bounds__(TPB, 2)
void rnn2_persistent(const float* __restrict__ x,
                     const float* __restrict__ Wih0, const float* __restrict__ Whh0,
                     const float* __restrict__ bih0, const float* __restrict__ bhh0,
                     const float* __restrict__ Wih1, const float* __restrict__ Whh1,
                     const float* __restrict__ bih1, const float* __restrict__ bhh1,
                     const float* __restrict__ Wfc,  const float* __restrict__ bfc,
                     float* __restrict__ out,
                     unsigned* __restrict__ runctr, unsigned* __restrict__ slots,
                     float* __restrict__ h0buf, float* __restrict__ h1buf)
{
  const int wg  = blockIdx.x;
  const int tid = threadIdx.x;
  __shared__ float lds[4096];
  float4* lds4 = (float4*)lds;

  // All WGs read this before barrier 0 completes; WG0 bumps it only after the
  // final barrier -> every WG sees the same base, values never repeat across replays.
  const unsigned runbase = __hip_atomic_load(runctr, __ATOMIC_RELAXED, __HIP_MEMORY_SCOPE_AGENT);

  if (wg < NWG0) {
    // ---------------- layer 0: 32 rows/WG, 16 threads/row ----------------
    const int cg  = tid & 15;        // column group within row
    const int row = wg * 32 + (tid >> 4);
    float4 wih[4], whh[32];
    {
      const float* wr = Wih0 + (size_t)row * I_DIM + cg * 4;
      #pragma unroll
      for (int k = 0; k < 4; ++k) wih[k] = *(const float4*)(wr + 64 * k);
      const float* wr2 = Whh0 + (size_t)row * H_DIM + cg * 4;
      #pragma unroll
      for (int k = 0; k < 32; ++k) whh[k] = *(const float4*)(wr2 + 64 * k);
    }
    const float bias = bih0[row] + bhh0[row];

    if (tid < 32) {  // zero owned rows, both parities (h0_0 = 0)
      h0buf[wg * 32 + tid] = 0.f;
      h0buf[H_DIM + wg * 32 + tid] = 0.f;
    }
    grid_barrier(slots, wg, tid, runbase + 1);

    for (int s = 1; s <= NSTEP; ++s) {
      if (s <= L_SEQ) {
        // stage x_t and h0_{s-1} into LDS (coalesced float4)
        const float4* xs = (const float4*)(x + (size_t)(s - 1) * I_DIM);
        if (tid < I_DIM / 4) lds4[tid] = xs[tid];
        const float4* hp = (const float4*)(h0buf + ((s - 1) & 1) * H_DIM);
        lds4[I_DIM / 4 + tid] = hp[tid];
        __syncthreads();
        float acc = 0.f;
        #pragma unroll
        for (int k = 0; k < 4; ++k) {
          float4 h4 = lds4[cg + 16 * k];
          acc += wih[k].x * h4.x + wih[k].y * h4.y + wih[k].z * h4.z + wih[k].w * h4.w;
        }
        #pragma unroll
        for (int k = 0; k < 32; ++k) {
          float4 h4 = lds4[I_DIM / 4 + cg + 16 * k];
          acc += whh[k].x * h4.x + whh[k].y * h4.y + whh[k].z * h4.z + whh[k].w * h4.w;
        }
        acc += __shfl_xor(acc, 1);
        acc += __shfl_xor(acc, 2);
        acc += __shfl_xor(acc, 4);
        acc += __shfl_xor(acc, 8);
        if (cg == 0) h0buf[(s & 1) * H_DIM + row] = tanhf(acc + bias);
      }
      grid_barrier(slots, wg, tid, runbase + 1 + (unsigned)s);
    }

    if (wg == 0) {
      // final FC: sigmoid(h1_L . Wfc + bfc); h1_8192 lives in parity 0
      float4 a = ((const float4*)h1buf)[tid];
      float4 b = ((const float4*)Wfc)[tid];
      float p = a.x * b.x + a.y * b.y + a.z * b.z + a.w * b.w;
      p += __shfl_xor(p, 1);  p += __shfl_xor(p, 2);  p += __shfl_xor(p, 4);
      p += __shfl_xor(p, 8);  p += __shfl_xor(p, 16); p += __shfl_xor(p, 32);
      if ((tid & 63) == 0) lds[tid >> 6] = p;
      __syncthreads();
      if (tid == 0) {
        float z = bfc[0];
        #pragma unroll
        for (int wv = 0; wv < TPB / 64; ++wv) z += lds[wv];
        out[0] = 1.f / (1.f + expf(-z));
        __hip_atomic_store(runctr, runbase + 9001u, __ATOMIC_RELAXED, __HIP_MEMORY_SCOPE_AGENT);
      }
    }
  } else {
    // ---------------- layer 1: 16 rows/WG, 32 threads/row ----------------
    const int cg  = tid & 31;
    const int row = (wg - NWG0) * 16 + (tid >> 5);
    float4 wih[16], whh[16];
    {
      const float* wr = Wih1 + (size_t)row * H_DIM + cg * 4;
      #pragma unroll
      for (int k = 0; k < 16; ++k) wih[k] = *(const float4*)(wr + 128 * k);
      const float* wr2 = Whh1 + (size_t)row * H_DIM + cg * 4;
      #pragma unroll
      for (int k = 0; k < 16; ++k) whh[k] = *(const float4*)(wr2 + 128 * k);
    }
    const float bias = bih1[row] + bhh1[row];

    if (tid < 16) {  // h1_0 = 0
      h1buf[(wg - NWG0) * 16 + tid] = 0.f;
      h1buf[H_DIM + (wg - NWG0) * 16 + tid] = 0.f;
    }
    grid_barrier(slots, wg, tid, runbase + 1);

    for (int s = 1; s <= NSTEP; ++s) {
      if (s >= 2) {  // compute h1_{s-1} from h0_{s-1}, h1_{s-2}
        const float4* h0p = (const float4*)(h0buf + ((s - 1) & 1) * H_DIM);
        const float4* h1p = (const float4*)(h1buf + ((s - 2) & 1) * H_DIM);
        lds4[tid] = h0p[tid];
        lds4[512 + tid] = h1p[tid];
        __syncthreads();
        float acc = 0.f;
        #pragma unroll
        for (int k = 0; k < 16; ++k) {
          float4 h4 = lds4[cg + 32 * k];
          acc += wih[k].x * h4.x + wih[k].y * h4.y + wih[k].z * h4.z + wih[k].w * h4.w;
        }
        #pragma unroll
        for (int k = 0; k < 16; ++k) {
          float4 h4 = lds4[512 + cg + 32 * k];
          acc += whh[k].x * h4.x + whh[k].y * h4.y + whh[k].z * h4.z + whh[k].w * h4.w;
        }
        acc += __shfl_xor(acc, 1);
        acc += __shfl_xor(acc, 2);
        acc += __shfl_xor(acc, 4);
        acc += __shfl_xor(acc, 8);
        acc += __shfl_xor(acc, 16);
        if (cg == 0) h1buf[((s - 1) & 1) * H_DIM + row] = tanhf(acc + bias);
      }
      grid_barrier(slots, wg, tid, runbase + 1 + (unsigned)s);
    }
  }
}

extern "C" void kernel_launch(void* const* d_in, const int* in_sizes, int n_in,
                              void* d_out, int out_size, void* d_ws, size_t ws_size,
                              hipStream_t stream) {
  const float* xx   = (const float*)d_in[0];
  const float* Wih0 = (const float*)d_in[1];
  const float* Whh0 = (const float*)d_in[2];
  const float* bih0 = (const float*)d_in[3];
  const float* bhh0 = (const float*)d_in[4];
  const float* Wih1 = (const float*)d_in[5];
  const float* Whh1 = (const float*)d_in[6];
  const float* bih1 = (const float*)d_in[7];
  const float* bhh1 = (const float*)d_in[8];
  const float* Wfc  = (const float*)d_in[9];
  const float* bfc  = (const float*)d_in[10];

  unsigned* runctr = (unsigned*)d_ws;
  unsigned* slots  = (unsigned*)((char*)d_ws + 256);
  float* h0buf     = (float*)((char*)d_ws + 1024);
  float* h1buf     = (float*)((char*)d_ws + 1024 + 2 * H_DIM * sizeof(float));

  rnn2_persistent<<<dim3(NWG), dim3(TPB), 0, stream>>>(
      xx, Wih0, Whh0, bih0, bhh0, Wih1, Whh1, bih1, bhh1, Wfc, bfc,
      (float*)d_out, runctr, slots, h0buf, h1buf);
}

// Round 2
// 40733.157 us; speedup vs baseline: 3.7427x; 3.7427x over previous
//
#include <hip/hip_runtime.h>
#include <math.h>

#define L_SEQ 8192
#define I_DIM 256
#define H_DIM 2048
#define NWG0  64
#define NWG1  128
#define NWG   (NWG0 + NWG1)
#define TPB   512
#define NSTEP (L_SEQ + 1)   // skewed 2-layer pipeline: 8193 compute steps

// ws layout (bytes): [0] runctr | [256..1024) slots | [1024) h0[2][2048] | [+16K) h1[2][2048]
//
// Coherence design: NO acquire/release fences (they emit buffer_wbl2/buffer_inv
// on gfx950 = whole-L2 maintenance per step, the round-1 disaster). Instead all
// cross-WG data moves via device-coherent accesses (sc0 sc1 -> bypass the
// non-coherent per-XCD L1/L2, served at the coherence point). Ordering:
// coherent h-store -> __syncthreads (drains vmcnt(0)) -> coherent slot store;
// consumer poll-load must complete before the branch exits, and VMEM issues
// in order, so the subsequent coherent h-load observes the published data.

__device__ __forceinline__ void cstore1(float* p, float v) {
  asm volatile("global_store_dword %0, %1, off sc0 sc1" :: "v"(p), "v"(v) : "memory");
}

__device__ __forceinline__ float4 cload4(const float* p) {
  float4 v;
  asm volatile("global_load_dwordx4 %0, %1, off sc0 sc1\n\ts_waitcnt vmcnt(0)"
               : "=v"(v) : "v"(p) : "memory");
  return v;
}

__device__ __forceinline__ void cload4x2(const float* p0, const float* p1, float4& a, float4& b) {
  asm volatile("global_load_dwordx4 %0, %2, off sc0 sc1\n\t"
               "global_load_dwordx4 %1, %3, off sc0 sc1\n\t"
               "s_waitcnt vmcnt(0)"
               : "=&v"(a), "=&v"(b) : "v"(p0), "v"(p1) : "memory");
}

__device__ __forceinline__ void grid_barrier(unsigned* slots, int wg, int tid, unsigned value) {
  __syncthreads();  // drains vmcnt(0): this WG's coherent stores are at the coherence point
  if (tid == 0)
    __hip_atomic_store(&slots[wg], value, __ATOMIC_RELAXED, __HIP_MEMORY_SCOPE_AGENT);
  if (tid < NWG) {
    // monotone-in-run values; (int)(slot - value) >= 0 tolerates run-ahead writers.
    while ((int)(__hip_atomic_load(&slots[tid], __ATOMIC_RELAXED, __HIP_MEMORY_SCOPE_AGENT) - value) < 0)
      __builtin_amdgcn_s_sleep(1);
  }
  __syncthreads();
}

__global__ __launch_bounds__(TPB, 2)
void rnn2_persistent(const float* __restrict__ x,
                     const float* __restrict__ Wih0, const float* __restrict__ Whh0,
                     const float* __restrict__ bih0, const float* __restrict__ bhh0,
                     const float* __restrict__ Wih1, const float* __restrict__ Whh1,
                     const float* __restrict__ bih1, const float* __restrict__ bhh1,
                     const float* __restrict__ Wfc,  const float* __restrict__ bfc,
                     float* __restrict__ out,
                     unsigned* __restrict__ runctr, unsigned* __restrict__ slots,
                     float* __restrict__ h0buf, float* __restrict__ h1buf)
{
  const int wg  = blockIdx.x;
  const int tid = threadIdx.x;
  __shared__ float lds[4096];
  float4* lds4 = (float4*)lds;

  // All WGs read this before barrier 0 completes; WG0 bumps it only after the
  // final barrier -> every WG sees the same base, values never repeat across replays.
  const unsigned runbase = __hip_atomic_load(runctr, __ATOMIC_RELAXED, __HIP_MEMORY_SCOPE_AGENT);

  if (wg < NWG0) {
    // ---------------- layer 0: 32 rows/WG, 16 threads/row ----------------
    const int cg  = tid & 15;        // column group within row
    const int row = wg * 32 + (tid >> 4);
    float4 wih[4], whh[32];
    {
      const float* wr = Wih0 + (size_t)row * I_DIM + cg * 4;
      #pragma unroll
      for (int k = 0; k < 4; ++k) wih[k] = *(const float4*)(wr + 64 * k);
      const float* wr2 = Whh0 + (size_t)row * H_DIM + cg * 4;
      #pragma unroll
      for (int k = 0; k < 32; ++k) whh[k] = *(const float4*)(wr2 + 64 * k);
    }
    const float bias = bih0[row] + bhh0[row];

    if (tid < 32) {  // zero owned rows, both parities (h0_0 = 0), coherent
      cstore1(&h0buf[wg * 32 + tid], 0.f);
      cstore1(&h0buf[H_DIM + wg * 32 + tid], 0.f);
    }
    grid_barrier(slots, wg, tid, runbase + 1);

    for (int s = 1; s <= NSTEP; ++s) {
      if (s <= L_SEQ) {
        // stage x_t (plain cached load -- L2 stays valid now) and h0_{s-1} (coherent)
        const float4* xs = (const float4*)(x + (size_t)(s - 1) * I_DIM);
        if (tid < I_DIM / 4) lds4[tid] = xs[tid];
        float4 hv = cload4(h0buf + ((s - 1) & 1) * H_DIM + tid * 4);
        lds4[I_DIM / 4 + tid] = hv;
        __syncthreads();
        float acc = 0.f;
        #pragma unroll
        for (int k = 0; k < 4; ++k) {
          float4 h4 = lds4[cg + 16 * k];
          acc += wih[k].x * h4.x + wih[k].y * h4.y + wih[k].z * h4.z + wih[k].w * h4.w;
        }
        #pragma unroll
        for (int k = 0; k < 32; ++k) {
          float4 h4 = lds4[I_DIM / 4 + cg + 16 * k];
          acc += whh[k].x * h4.x + whh[k].y * h4.y + whh[k].z * h4.z + whh[k].w * h4.w;
        }
        acc += __shfl_xor(acc, 1);
        acc += __shfl_xor(acc, 2);
        acc += __shfl_xor(acc, 4);
        acc += __shfl_xor(acc, 8);
        if (cg == 0) cstore1(&h0buf[(s & 1) * H_DIM + row], tanhf(acc + bias));
      }
      grid_barrier(slots, wg, tid, runbase + 1 + (unsigned)s);
    }

    if (wg == 0) {
      // final FC: sigmoid(h1_L . Wfc + bfc); h1_8192 lives in parity 0
      float4 a = cload4((const float*)h1buf + tid * 4);
      float4 b = ((const float4*)Wfc)[tid];
      float p = a.x * b.x + a.y * b.y + a.z * b.z + a.w * b.w;
      p += __shfl_xor(p, 1);  p += __shfl_xor(p, 2);  p += __shfl_xor(p, 4);
      p += __shfl_xor(p, 8);  p += __shfl_xor(p, 16); p += __shfl_xor(p, 32);
      if ((tid & 63) == 0) lds[tid >> 6] = p;
      __syncthreads();
      if (tid == 0) {
        float z = bfc[0];
        #pragma unroll
        for (int wv = 0; wv < TPB / 64; ++wv) z += lds[wv];
        out[0] = 1.f / (1.f + expf(-z));
        __hip_atomic_store(runctr, runbase + 9001u, __ATOMIC_RELAXED, __HIP_MEMORY_SCOPE_AGENT);
      }
    }
  } else {
    // ---------------- layer 1: 16 rows/WG, 32 threads/row ----------------
    const int cg  = tid & 31;
    const int row = (wg - NWG0) * 16 + (tid >> 5);
    float4 wih[16], whh[16];
    {
      const float* wr = Wih1 + (size_t)row * H_DIM + cg * 4;
      #pragma unroll
      for (int k = 0; k < 16; ++k) wih[k] = *(const float4*)(wr + 128 * k);
      const float* wr2 = Whh1 + (size_t)row * H_DIM + cg * 4;
      #pragma unroll
      for (int k = 0; k < 16; ++k) whh[k] = *(const float4*)(wr2 + 128 * k);
    }
    const float bias = bih1[row] + bhh1[row];

    if (tid < 16) {  // h1_0 = 0, both parities, coherent
      cstore1(&h1buf[(wg - NWG0) * 16 + tid], 0.f);
      cstore1(&h1buf[H_DIM + (wg - NWG0) * 16 + tid], 0.f);
    }
    grid_barrier(slots, wg, tid, runbase + 1);

    for (int s = 1; s <= NSTEP; ++s) {
      if (s >= 2) {  // compute h1_{s-1} from h0_{s-1}, h1_{s-2}
        float4 a, b;
        cload4x2(h0buf + ((s - 1) & 1) * H_DIM + tid * 4,
                 h1buf + ((s - 2) & 1) * H_DIM + tid * 4, a, b);
        lds4[tid] = a;
        lds4[512 + tid] = b;
        __syncthreads();
        float acc = 0.f;
        #pragma unroll
        for (int k = 0; k < 16; ++k) {
          float4 h4 = lds4[cg + 32 * k];
          acc += wih[k].x * h4.x + wih[k].y * h4.y + wih[k].z * h4.z + wih[k].w * h4.w;
        }
        #pragma unroll
        for (int k = 0; k < 16; ++k) {
          float4 h4 = lds4[512 + cg + 32 * k];
          acc += whh[k].x * h4.x + whh[k].y * h4.y + whh[k].z * h4.z + whh[k].w * h4.w;
        }
        acc += __shfl_xor(acc, 1);
        acc += __shfl_xor(acc, 2);
        acc += __shfl_xor(acc, 4);
        acc += __shfl_xor(acc, 8);
        acc += __shfl_xor(acc, 16);
        if (cg == 0) cstore1(&h1buf[((s - 1) & 1) * H_DIM + row], tanhf(acc + bias));
      }
      grid_barrier(slots, wg, tid, runbase + 1 + (unsigned)s);
    }
  }
}

extern "C" void kernel_launch(void* const* d_in, const int* in_sizes, int n_in,
                              void* d_out, int out_size, void* d_ws, size_t ws_size,
                              hipStream_t stream) {
  const float* xx   = (const float*)d_in[0];
  const float* Wih0 = (const float*)d_in[1];
  const float* Whh0 = (const float*)d_in[2];
  const float* bih0 = (const float*)d_in[3];
  const float* bhh0 = (const float*)d_in[4];
  const float* Wih1 = (const float*)d_in[5];
  const float* Whh1 = (const float*)d_in[6];
  const float* bih1 = (const float*)d_in[7];
  const float* bhh1 = (const float*)d_in[8];
  const float* Wfc  = (const float*)d_in[9];
  const float* bfc  = (const float*)d_in[10];

  unsigned* runctr = (unsigned*)d_ws;
  unsigned* slots  = (unsigned*)((char*)d_ws + 256);
  float* h0buf     = (float*)((char*)d_ws + 1024);
  float* h1buf     = (float*)((char*)d_ws + 1024 + 2 * H_DIM * sizeof(float));

  rnn2_persistent<<<dim3(NWG), dim3(TPB), 0, stream>>>(
      xx, Wih0, Whh0, bih0, bhh0, Wih1, Whh1, bih1, bhh1, Wfc, bfc,
      (float*)d_out, runctr, slots, h0buf, h1buf);
}